// Round 3
// baseline (182.638 us; speedup 1.0000x reference)
//
#include <hip/hip_runtime.h>

#define NB 32
#define NS 2048
#define NH 1024
#define WIN 15   // exp(sc-lse-0.5*d^2) underflows to 0.0f beyond |d|>~15+scores spread

// ---------------- K1: v[b,h] = sum_d dec[b,d] * Wa[d,h]; zero denom/done counters.
// grid = 16 ht * 32 b (b fastest -> same Wa tile co-scheduled for L2 reuse)
__global__ __launch_bounds__(256) void k1_v(const float* __restrict__ dec,
                                            const float* __restrict__ Wa,
                                            float* __restrict__ v,
                                            double* __restrict__ denomD,
                                            int* __restrict__ done) {
    __shared__ float red[256];
    int blk = blockIdx.x;
    int b = blk & 31, ht = blk >> 5;
    int t = threadIdx.x;
    if (blk == 0 && t < NB) { denomD[t] = 0.0; done[t] = 0; }

    int ds = t >> 6, h_loc = t & 63;
    int h = ht * 64 + h_loc;
    const float* decb = dec + b * NH + ds * 256;
    const float* wa   = Wa + (size_t)(ds * 256) * NH + h;
    float acc = 0.f;
#pragma unroll 8
    for (int d = 0; d < 256; ++d)
        acc = fmaf(decb[d], wa[(size_t)d * NH], acc);
    red[t] = acc;
    __syncthreads();
    if (t < 64)
        v[b * NH + ht * 64 + t] = red[t] + red[t + 64] + red[t + 128] + red[t + 192];
}

// ---------------- K2: fused scores + denom + (last block per b) attn + ctx
// grid = 2048 blocks; block handles 32 global rows; 64 blocks per b.
__global__ __launch_bounds__(256) void k2_main(const float* __restrict__ enc,
                                               const float* __restrict__ v,
                                               const int* __restrict__ ts,
                                               float* __restrict__ scores,
                                               double* __restrict__ denomD,
                                               int* __restrict__ done,
                                               float* __restrict__ ctx,
                                               float* __restrict__ attn) {
    __shared__ float vs[NH];
    __shared__ float rowsc[32];
    __shared__ int winner;
    int blk = blockIdx.x;
    int t = threadIdx.x;
    int b = blk >> 6;
    int row0 = blk << 5;               // global row = b*NS + s
    int wid = t >> 6, lane = t & 63;

    ((float4*)vs)[t] = ((const float4*)(v + b * NH))[t];
    __syncthreads();

    // ---- stream 8 rows per wave, 8 accumulators ----
    const float4* vv = (const float4*)vs;
    int r0 = row0 + wid * 8;
    const float4* eb = (const float4*)(enc + (size_t)r0 * NH);
    float acc[8];
#pragma unroll
    for (int r = 0; r < 8; ++r) acc[r] = 0.f;
#pragma unroll
    for (int k = 0; k < 4; ++k) {
        float4 bv = vv[k * 64 + lane];
#pragma unroll
        for (int r = 0; r < 8; ++r) {
            float4 a = eb[r * 256 + k * 64 + lane];
            acc[r] = fmaf(a.x, bv.x, acc[r]);
            acc[r] = fmaf(a.y, bv.y, acc[r]);
            acc[r] = fmaf(a.z, bv.z, acc[r]);
            acc[r] = fmaf(a.w, bv.w, acc[r]);
        }
    }
#pragma unroll
    for (int r = 0; r < 8; ++r) {
        float s = acc[r];
#pragma unroll
        for (int off = 32; off >= 1; off >>= 1) s += __shfl_xor(s, off, 64);
        if (lane == 0) rowsc[wid * 8 + r] = s;
    }
    __syncthreads();

    // ---- wave 0: store scores (coalesced), partial denom, arrive counter ----
    if (wid == 0) {
        float sc_t = (lane < 32) ? rowsc[lane] : 0.f;
        if (lane < 32) scores[row0 + lane] = sc_t;
        double e = (lane < 32) ? exp((double)sc_t) : 0.0;
#pragma unroll
        for (int off = 32; off >= 1; off >>= 1) e += __shfl_xor(e, off, 64);
        if (lane == 0) {
            atomicAdd(&denomD[b], e);
            __threadfence();                       // release: wb L2 so scores/denom visible
            int old = atomicAdd(&done[b], 1);
            winner = (old == 63) ? 1 : 0;
        }
    }
    __syncthreads();

    // ---- last block of this b: epilogue (attn all S, ctx over gaussian window) ----
    if (winner) {
        __threadfence();                           // acquire: invalidate stale lines
        double den = denomD[b];
        float lse = (float)log(den);
        int p = ts[b];
        float pf = (float)p;
        const float* sb = scores + (size_t)b * NS;
#pragma unroll
        for (int k = 0; k < 8; ++k) {
            int s = t + 256 * k;
            float d = (float)s - pf;
            attn[(size_t)b * NS + s] = expf(sb[s] - lse - 0.5f * d * d);
        }
        int w0 = max(0, p - WIN), w1 = min(NS - 1, p + WIN);
        float c0 = 0.f, c1 = 0.f, c2 = 0.f, c3 = 0.f;
        for (int r = w0; r <= w1; ++r) {
            float dr = (float)r - pf;
            float w = expf(sb[r] - lse - 0.5f * dr * dr);
            const float* er = enc + ((size_t)b * NS + r) * NH;
            c0 = fmaf(w, er[t],       c0);
            c1 = fmaf(w, er[t + 256], c1);
            c2 = fmaf(w, er[t + 512], c2);
            c3 = fmaf(w, er[t + 768], c3);
        }
        ctx[b * NH + t]       = c0;
        ctx[b * NH + t + 256] = c1;
        ctx[b * NH + t + 512] = c2;
        ctx[b * NH + t + 768] = c3;
    }
}

extern "C" void kernel_launch(void* const* d_in, const int* in_sizes, int n_in,
                              void* d_out, int out_size, void* d_ws, size_t ws_size,
                              hipStream_t stream) {
    const float* enc  = (const float*)d_in[0];   // [B,S,H]
    const float* dec  = (const float*)d_in[1];   // [B,H]
    const int*   ts   = (const int*)d_in[2];     // [B]
    const float* Wa_w = (const float*)d_in[3];   // [H,H]
    // d_in[4] = Wa_b: uniform per-b score shift -> softmax-invariant, dropped.

    float* out  = (float*)d_out;
    float* ctx  = out;             // [B,H]
    float* attn = out + NB * NH;   // [B,S]

    float*  v      = (float*)d_ws;                  // NB*NH floats
    float*  scores = v + NB * NH;                   // NB*NS floats
    double* denomD = (double*)(scores + NB * NS);   // NB doubles (8B-aligned)
    int*    done   = (int*)(denomD + NB);           // NB ints

    k1_v   <<<512,  256, 0, stream>>>(dec, Wa_w, v, denomD, done);
    k2_main<<<2048, 256, 0, stream>>>(enc, v, ts, scores, denomD, done, ctx, attn);
}

// Round 4
// 77.985 us; speedup vs baseline: 2.3420x; 2.3420x over previous
//
#include <hip/hip_runtime.h>

#define NB 32
#define NS 2048
#define NH 1024
#define WIN 15   // exp(sc-lse-0.5*d^2): score-lse<=0, so |d|>15 underflows to 0.0f (matches ref)

// ---------------- K1: v[b,h] = sum_d dec[b,d]*Wa[d,h]; also zero ctx and denomD.
// grid = 16 ht * 32 b (b fastest -> 32 co-scheduled blocks share one 256KB Wa tile in L2)
__global__ __launch_bounds__(256) void k1_v(const float* __restrict__ dec,
                                            const float* __restrict__ Wa,
                                            float* __restrict__ v,
                                            double* __restrict__ denomD,
                                            float* __restrict__ ctx) {
    __shared__ float red[256];
    int blk = blockIdx.x;
    int b = blk & 31, ht = blk >> 5;
    int t = threadIdx.x;
    if (blk == 0 && t < NB) denomD[t] = 0.0;
    if (blk < 128) ctx[blk * 256 + t] = 0.f;       // NB*NH = 128*256

    int ds = t >> 6, hl = t & 63;
    int h = ht * 64 + hl;
    const float* decb = dec + b * NH + ds * 256;
    const float* wa   = Wa + (size_t)(ds * 256) * NH + h;
    float a0 = 0.f, a1 = 0.f, a2 = 0.f, a3 = 0.f;
#pragma unroll 2
    for (int d = 0; d < 256; d += 4) {             // 4 split accumulators: no dep chain
        a0 = fmaf(decb[d],     wa[(size_t)d * NH],       a0);
        a1 = fmaf(decb[d + 1], wa[(size_t)(d + 1) * NH], a1);
        a2 = fmaf(decb[d + 2], wa[(size_t)(d + 2) * NH], a2);
        a3 = fmaf(decb[d + 3], wa[(size_t)(d + 3) * NH], a3);
    }
    red[t] = (a0 + a1) + (a2 + a3);
    __syncthreads();
    if (t < 64)
        v[b * NH + ht * 64 + t] = red[t] + red[t + 64] + red[t + 128] + red[t + 192];
}

// ---------------- K2: scores[b,s] = enc[b,s,:].v[b,:]; partial denom per block.
// v held in 16 REGISTERS per lane (no LDS in hot loop). 4 rows/wave, 16 rows/block,
// 4096 blocks. 16 independent dwordx4 loads in flight per lane.
__global__ __launch_bounds__(256) void k2_scores(const float* __restrict__ enc,
                                                 const float* __restrict__ v,
                                                 float* __restrict__ scores,
                                                 double* __restrict__ denomD) {
    __shared__ float vs[NH];
    __shared__ float rowsc[16];
    int t = threadIdx.x, wid = t >> 6, lane = t & 63;
    int b = blockIdx.x >> 7;           // 128 blocks per b
    int row0 = blockIdx.x << 4;        // global row (b*NS + s)

    ((float4*)vs)[t] = ((const float4*)(v + b * NH))[t];
    __syncthreads();
    const float4* vv = (const float4*)vs;
    float4 vr0 = vv[lane], vr1 = vv[64 + lane], vr2 = vv[128 + lane], vr3 = vv[192 + lane];

    int r0 = row0 + wid * 4;
    const float4* eb = (const float4*)(enc + (size_t)r0 * NH);
    float acc[4];
#pragma unroll
    for (int r = 0; r < 4; ++r) {
        float4 x0 = eb[r * 256 + lane];
        float4 x1 = eb[r * 256 + 64 + lane];
        float4 x2 = eb[r * 256 + 128 + lane];
        float4 x3 = eb[r * 256 + 192 + lane];
        float s = 0.f;
        s = fmaf(x0.x, vr0.x, s); s = fmaf(x0.y, vr0.y, s);
        s = fmaf(x0.z, vr0.z, s); s = fmaf(x0.w, vr0.w, s);
        s = fmaf(x1.x, vr1.x, s); s = fmaf(x1.y, vr1.y, s);
        s = fmaf(x1.z, vr1.z, s); s = fmaf(x1.w, vr1.w, s);
        s = fmaf(x2.x, vr2.x, s); s = fmaf(x2.y, vr2.y, s);
        s = fmaf(x2.z, vr2.z, s); s = fmaf(x2.w, vr2.w, s);
        s = fmaf(x3.x, vr3.x, s); s = fmaf(x3.y, vr3.y, s);
        s = fmaf(x3.z, vr3.z, s); s = fmaf(x3.w, vr3.w, s);
        acc[r] = s;
    }
#pragma unroll
    for (int r = 0; r < 4; ++r) {
        float s = acc[r];
#pragma unroll
        for (int off = 32; off >= 1; off >>= 1) s += __shfl_xor(s, off, 64);
        if (lane == 0) { scores[r0 + r] = s; rowsc[wid * 4 + r] = s; }
    }
    __syncthreads();
    if (t < 16) {                       // 16 row-partials -> one f64 atomic
        double e = exp((double)rowsc[t]);
#pragma unroll
        for (int off = 8; off >= 1; off >>= 1) e += __shfl_xor(e, off, 64);
        if (t == 0) atomicAdd(&denomD[b], e);
    }
}

// ---------------- K3: attn = exp(score - lse - 0.5 d^2); windowed ctx via atomics.
// grid = 32 b * 8 s-chunks
__global__ __launch_bounds__(256) void k3_out(const float* __restrict__ enc,
                                              const float* __restrict__ scores,
                                              const int* __restrict__ ts,
                                              const double* __restrict__ denomD,
                                              float* __restrict__ ctx,
                                              float* __restrict__ attn) {
    int b = blockIdx.x >> 3;
    int c = blockIdx.x & 7;
    int t = threadIdx.x;

    float lse = (float)log(denomD[b]);
    int p = ts[b];
    float pf = (float)p;

    int s = c * 256 + t;
    float sc = scores[b * NS + s];
    float d = (float)s - pf;
    attn[(size_t)b * NS + s] = expf(sc - lse - 0.5f * d * d);

    int w0 = max(0, p - WIN), w1 = min(NS - 1, p + WIN);
    int r0 = max(w0, c * 256), r1 = min(w1, c * 256 + 255);
    if (r0 <= r1) {
        const float* sb = scores + (size_t)b * NS;
        float a0 = 0.f, a1 = 0.f, a2 = 0.f, a3 = 0.f;
        for (int r = r0; r <= r1; ++r) {
            float dr = (float)r - pf;
            float w = expf(sb[r] - lse - 0.5f * dr * dr);
            const float* er = enc + ((size_t)b * NS + r) * NH;
            a0 = fmaf(w, er[t],       a0);
            a1 = fmaf(w, er[t + 256], a1);
            a2 = fmaf(w, er[t + 512], a2);
            a3 = fmaf(w, er[t + 768], a3);
        }
        atomicAdd(&ctx[b * NH + t],       a0);
        atomicAdd(&ctx[b * NH + t + 256], a1);
        atomicAdd(&ctx[b * NH + t + 512], a2);
        atomicAdd(&ctx[b * NH + t + 768], a3);
    }
}

extern "C" void kernel_launch(void* const* d_in, const int* in_sizes, int n_in,
                              void* d_out, int out_size, void* d_ws, size_t ws_size,
                              hipStream_t stream) {
    const float* enc  = (const float*)d_in[0];   // [B,S,H]
    const float* dec  = (const float*)d_in[1];   // [B,H]
    const int*   ts   = (const int*)d_in[2];     // [B]
    const float* Wa_w = (const float*)d_in[3];   // [H,H]
    // d_in[4] = Wa_b: uniform per-b score shift -> softmax-invariant, dropped.

    float* out  = (float*)d_out;
    float* ctx  = out;             // [B,H]
    float* attn = out + NB * NH;   // [B,S]

    float*  v      = (float*)d_ws;                  // NB*NH floats
    float*  scores = v + NB * NH;                   // NB*NS floats
    double* denomD = (double*)(scores + NB * NS);   // NB doubles (8B-aligned)

    k1_v     <<<512,  256, 0, stream>>>(dec, Wa_w, v, denomD, ctx);
    k2_scores<<<4096, 256, 0, stream>>>(enc, v, scores, denomD);
    k3_out   <<<NB*8, 256, 0, stream>>>(enc, scores, ts, denomD, ctx, attn);
}